// Round 2
// baseline (538.718 us; speedup 1.0000x reference)
//
#include <hip/hip_runtime.h>

// Luong 'general' attention, B=4 D=256 L=4096.
//   out[b,o,d] = softmax_q( (q W^T + b_in)[o,:] . c[q,:] ) @ c     (+ full weights matrix)
// K0 transpose/cast q,c -> [B][L][D] f16 ; K0b W f32->f16 ; K1 MFMA linear qw=q@W^T+b ;
// K0c context cast [B][D][L] f32->f16 (aliases qT16, dead after K1) ;
// K2 fused attn: phase A l=sum(exp(s)) (no max-sub: |s|<~35, f32 exp safe);
//                phase B recompute s (bit-identical), w=exp(s)/l -> global+LDS,
//                PV MFMA with B-frags read DIRECTLY from cD16 (q-innermost, no tr-read).
// ws usage: 25.3 MB.

#define BATCH 4
#define DDIM  256
#define LSEQ  4096
#define TQ    64

typedef float    f32x4 __attribute__((ext_vector_type(4)));
typedef _Float16 f16x8 __attribute__((ext_vector_type(8)));
typedef _Float16 f16x4 __attribute__((ext_vector_type(4)));
typedef int      i32x4 __attribute__((ext_vector_type(4)));

// ---------------- K0: [B][D][L] f32 -> [B][L][D] f16 (query & context) ------
__global__ __launch_bounds__(256) void transpose_cast(
    const float* __restrict__ q_in, const float* __restrict__ c_in,
    _Float16* __restrict__ q_out, _Float16* __restrict__ c_out)
{
  __shared__ float tile[64][68];
  const int which = blockIdx.z >> 2;
  const int b     = blockIdx.z & 3;
  const float* __restrict__ src = which ? c_in : q_in;
  _Float16* __restrict__ dst    = which ? c_out : q_out;
  const int l0 = blockIdx.x * 64, d0 = blockIdx.y * 64;
  const int tid = threadIdx.x;
  const int tr = tid >> 4, tc = (tid & 15) << 2;
#pragma unroll
  for (int i = 0; i < 4; ++i) {
    int d = tr + i * 16;
    f32x4 v = *(const f32x4*)(src + ((size_t)b * DDIM + d0 + d) * LSEQ + l0 + tc);
    *(f32x4*)&tile[d][tc] = v;
  }
  __syncthreads();
#pragma unroll
  for (int i = 0; i < 4; ++i) {
    int l = tr + i * 16;
    f16x4 h;
    h[0] = (_Float16)tile[tc + 0][l];
    h[1] = (_Float16)tile[tc + 1][l];
    h[2] = (_Float16)tile[tc + 2][l];
    h[3] = (_Float16)tile[tc + 3][l];
    *(f16x4*)(dst + ((size_t)b * LSEQ + l0 + l) * DDIM + d0 + tc) = h;
  }
}

// ---------------- K0b: W f32 -> f16 -----------------------------------------
__global__ __launch_bounds__(256) void wconv(const float* __restrict__ w,
                                             _Float16* __restrict__ w16) {
  int i = (blockIdx.x * 256 + threadIdx.x) * 4;
  f32x4 v = *(const f32x4*)(w + i);
  f16x4 h;
  h[0] = (_Float16)v[0]; h[1] = (_Float16)v[1];
  h[2] = (_Float16)v[2]; h[3] = (_Float16)v[3];
  *(f16x4*)(w16 + i) = h;
}

// ---------------- K0c: context [B][D][L] f32 -> f16 (same layout, pure cast)-
__global__ __launch_bounds__(256) void castD(const float* __restrict__ c_in,
                                             _Float16* __restrict__ cD16) {
  size_t i = ((size_t)blockIdx.x * 256 + threadIdx.x) * 8;
  f32x4 a = *(const f32x4*)(c_in + i);
  f32x4 b = *(const f32x4*)(c_in + i + 4);
  f16x8 h;
  h[0] = (_Float16)a[0]; h[1] = (_Float16)a[1];
  h[2] = (_Float16)a[2]; h[3] = (_Float16)a[3];
  h[4] = (_Float16)b[0]; h[5] = (_Float16)b[1];
  h[6] = (_Float16)b[2]; h[7] = (_Float16)b[3];
  *(f16x8*)(cD16 + i) = h;
}

// ---------------- K1: qw16 = qT16 @ W^T + bias  ([16384,256]x[256,256]) -----
__global__ __launch_bounds__(256) void linear_q(
    const _Float16* __restrict__ qT16, const _Float16* __restrict__ W16,
    const float* __restrict__ bias, _Float16* __restrict__ qw16)
{
  const int tid = threadIdx.x;
  const int wv = tid >> 6, ln = tid & 63, g = ln >> 4, c16 = ln & 15;
  const size_t r0 = (size_t)blockIdx.x * 64 + wv * 16;

  f16x8 qa[8];
  const _Float16* qrow = qT16 + (r0 + c16) * DDIM + g * 8;
#pragma unroll
  for (int kk = 0; kk < 8; ++kk) qa[kk] = *(const f16x8*)(qrow + kk * 32);

  f32x4 acc[16];
#pragma unroll
  for (int n = 0; n < 16; ++n) acc[n] = f32x4{0.f, 0.f, 0.f, 0.f};

#pragma unroll 2
  for (int kk = 0; kk < 8; ++kk) {
#pragma unroll
    for (int n = 0; n < 16; ++n) {
      f16x8 bf = *(const f16x8*)(W16 + (n * 16 + c16) * DDIM + kk * 32 + g * 8);
      acc[n] = __builtin_amdgcn_mfma_f32_16x16x32_f16(qa[kk], bf, acc[n], 0, 0, 0);
    }
  }
#pragma unroll
  for (int n = 0; n < 16; ++n) {
    float bb = bias[n * 16 + c16];
#pragma unroll
    for (int r = 0; r < 4; ++r)
      qw16[(r0 + 4 * g + r) * DDIM + n * 16 + c16] = (_Float16)(acc[n][r] + bb);
  }
}

// ---------------- K2: fused attention ---------------------------------------
// c_lds layout (scores B-operand): halfword idx = (d>>4)*1024 + q*16 + (d&15),
// byte swizzle ^((q&4)<<2).  Gives ds_read_b128 of 8 consecutive d at fixed q.
// PV B-operand comes straight from cD16 [B][D][L] (8 consecutive q at fixed d).
__global__ __launch_bounds__(256) void attn_main(
    const _Float16* __restrict__ qw16,
    const _Float16* __restrict__ cT16,
    const _Float16* __restrict__ cD16,
    float* __restrict__ outp,
    float* __restrict__ wgt)
{
  __shared__ __align__(16) unsigned short c_lds[16384]; // 32 KB
  __shared__ __align__(16) unsigned short w_lds[4096];  // 8 KB (P tile, per-wave 16x64)

  const int tid = threadIdx.x;
  const int wv  = tid >> 6;
  const int ln  = tid & 63;
  const int g   = ln >> 4;
  const int c16 = ln & 15;

  // remap so each XCD pair works one batch (context f16 = 2MB/layout, fits XCD L2)
  const int lin   = blockIdx.y * 64 + blockIdx.x;
  const int b     = (lin & 7) >> 1;
  const int otile = ((lin >> 3) << 1) | (lin & 1);
  const int o0    = otile * 64;
  const int bo    = b * LSEQ + o0;

  const _Float16* __restrict__ cbase = cT16 + (size_t)b * LSEQ * DDIM;
  const _Float16* __restrict__ cDb   = cD16 + (size_t)b * DDIM * LSEQ;

  // qw A-frags: wave's 16 rows, K=256 (8 k-steps)
  f16x8 qa[8];
  {
    const _Float16* qrow = qw16 + ((size_t)bo + wv * 16 + c16) * DDIM + g * 8;
#pragma unroll
    for (int kk = 0; kk < 8; ++kk) qa[kk] = *(const f16x8*)(qrow + kk * 32);
  }

  const unsigned sb_base =
      ((unsigned)((g >> 1) * 2048 + c16 * 32 + (g & 1) * 16)) ^ ((unsigned)((c16 & 4) << 2));

  auto stage = [&](int q0) {
    i32x4 v[8]; unsigned dstb[8];
#pragma unroll
    for (int i = 0; i < 8; ++i) {
      int idx = tid + i * 256;
      int q   = (idx >> 3) & 63;
      int d0  = ((idx & 7) << 3) + ((idx >> 9) << 6);
      v[i] = *(const i32x4*)(cbase + (size_t)(q0 + q) * DDIM + d0);
      unsigned byte = (unsigned)((d0 >> 4) * 2048 + q * 32 + (d0 & 15) * 2);
      dstb[i] = byte ^ (unsigned)((q & 4) << 2);
    }
#pragma unroll
    for (int i = 0; i < 8; ++i) *(i32x4*)((char*)c_lds + dstb[i]) = v[i];
  };

  auto scores = [&](f32x4 sa[4]) {
#pragma unroll
    for (int qf = 0; qf < 4; ++qf) sa[qf] = f32x4{0.f, 0.f, 0.f, 0.f};
#pragma unroll
    for (int kk = 0; kk < 8; ++kk) {
#pragma unroll
      for (int qf = 0; qf < 4; ++qf) {
        f16x8 bf = *(const f16x8*)((const char*)c_lds + (sb_base + kk * 4096 + qf * 512));
        sa[qf] = __builtin_amdgcn_mfma_f32_16x16x32_f16(qa[kk], bf, sa[qf], 0, 0, 0);
      }
    }
  };

  // ---- phase A: per-row sum of exp(s)
  float lsum[4] = {0.f, 0.f, 0.f, 0.f};
  for (int q0 = 0; q0 < LSEQ; q0 += TQ) {
    __syncthreads();
    stage(q0);
    __syncthreads();
    f32x4 sa[4];
    scores(sa);
#pragma unroll
    for (int qf = 0; qf < 4; ++qf)
#pragma unroll
      for (int r = 0; r < 4; ++r) lsum[r] += __expf(sa[qf][r]);
  }

  float invl[4];
#pragma unroll
  for (int r = 0; r < 4; ++r) {
    float v = lsum[r];
    v += __shfl_xor(v, 1);
    v += __shfl_xor(v, 2);
    v += __shfl_xor(v, 4);
    v += __shfl_xor(v, 8);
    invl[r] = 1.0f / v;
  }

  // ---- phase B: recompute scores, write weights, PV accumulate
  f32x4 oacc[16];
#pragma unroll
  for (int n = 0; n < 16; ++n) oacc[n] = f32x4{0.f, 0.f, 0.f, 0.f};

  for (int q0 = 0; q0 < LSEQ; q0 += TQ) {
    __syncthreads();
    stage(q0);
    __syncthreads();
    f32x4 sa[4];
    scores(sa);

#pragma unroll
    for (int qf = 0; qf < 4; ++qf) {
#pragma unroll
      for (int r = 0; r < 4; ++r) {
        float w = __expf(sa[qf][r]) * invl[r];
        wgt[(size_t)(bo + wv * 16 + 4 * g + r) * LSEQ + (q0 + qf * 16 + c16)] = w;
        unsigned wb = (unsigned)(wv * 2048 + (4 * g + r) * 128 + (qf * 16 + c16) * 2);
        wb ^= (unsigned)(((4 * g + r) & 7) << 4);
        *(_Float16*)((char*)w_lds + wb) = (_Float16)w;
      }
    }
    // order w_lds writes (whole wave) before A-frag reads
    asm volatile("s_waitcnt lgkmcnt(0)" ::: "memory");
    __builtin_amdgcn_sched_barrier(0);

#pragma unroll
    for (int kq = 0; kq < 2; ++kq) {
      unsigned ab = ((unsigned)(wv * 2048 + c16 * 128 + (kq * 32 + g * 8) * 2)) ^
                    ((unsigned)((c16 & 7) << 4));
      f16x8 wa = *(const f16x8*)((const char*)w_lds + ab);
      // B-frags from global cD16: lane reads c[q0+kq*32+g*8 .. +7][n*16+c16]
      const _Float16* src = cDb + (size_t)c16 * LSEQ + q0 + kq * 32 + g * 8;
      f16x8 bf[16];
#pragma unroll
      for (int n = 0; n < 16; ++n)
        bf[n] = *(const f16x8*)(src + (size_t)(n * 16) * LSEQ);
#pragma unroll
      for (int n = 0; n < 16; ++n)
        oacc[n] = __builtin_amdgcn_mfma_f32_16x16x32_f16(wa, bf[n], oacc[n], 0, 0, 0);
    }
  }

  // ---- epilogue: out (already normalized)
#pragma unroll
  for (int n = 0; n < 16; ++n)
#pragma unroll
    for (int r = 0; r < 4; ++r)
      outp[(size_t)(bo + wv * 16 + 4 * g + r) * DDIM + n * 16 + c16] = oacc[n][r];
}

extern "C" void kernel_launch(void* const* d_in, const int* in_sizes, int n_in,
                              void* d_out, int out_size, void* d_ws, size_t ws_size,
                              hipStream_t stream) {
  const float* query   = (const float*)d_in[0];
  const float* context = (const float*)d_in[1];
  const float* W_in    = (const float*)d_in[2];
  const float* b_in    = (const float*)d_in[3];

  float* outp = (float*)d_out;
  float* wgt  = outp + (size_t)BATCH * LSEQ * DDIM;  // outputs concat: out, weights

  const size_t NELEM = (size_t)BATCH * LSEQ * DDIM;  // 4,194,304
  _Float16* qT16 = (_Float16*)d_ws;
  _Float16* cT16 = qT16 + NELEM;
  _Float16* qw16 = cT16 + NELEM;
  _Float16* W16  = qw16 + NELEM;   // +65536 halfs; total ws use = 25.3 MB
  _Float16* cD16 = qT16;           // aliases qT16 (dead after linear_q)

  transpose_cast<<<dim3(LSEQ / 64, DDIM / 64, 2 * BATCH), 256, 0, stream>>>(
      query, context, qT16, cT16);
  wconv<<<(DDIM * DDIM) / 1024, 256, 0, stream>>>(W_in, W16);
  linear_q<<<(BATCH * LSEQ) / 64, 256, 0, stream>>>(qT16, W16, b_in, qw16);
  castD<<<(int)(NELEM / 2048), 256, 0, stream>>>(context, cD16);
  attn_main<<<dim3(64, BATCH), 256, 0, stream>>>(qw16, cT16, cD16, outp, wgt);
}

// Round 5
// 316.459 us; speedup vs baseline: 1.7023x; 1.7023x over previous
//
#include <hip/hip_runtime.h>

// Luong 'general' attention, B=4 D=256 L=4096.
// K0 transpose/cast q,c -> [B][L][D] f16 ; K0b W f32->f16 ; K1 MFMA linear qw=q@W^T+b ;
// K0c context cast [B][D][L] f32->f16 (aliases qT16, dead after K1) ;
// K2 fused attn, double-buffered global_load_lds staging:
//   phase A: l=sum(exp(s)) per row (no max-sub: |s|<~35, f32 exp safe)
//   phase B: recompute s (bit-identical), w=exp(s)/l -> global + w_lds(f16),
//            PV from c_lds2 (d-major LDS) with n-slice wave decomposition.
// LDS: 2 x (32KB c_lds q-major + 32KB c_lds2 d-major) + 8KB w_lds = 136 KB.
// ws usage: 25.3 MB.

#define BATCH 4
#define DDIM  256
#define LSEQ  4096
#define TQ    64

typedef float    f32x4 __attribute__((ext_vector_type(4)));
typedef _Float16 f16x8 __attribute__((ext_vector_type(8)));
typedef _Float16 f16x4 __attribute__((ext_vector_type(4)));

__device__ __forceinline__ void gld16(const void* g, void* l) {
  __builtin_amdgcn_global_load_lds((const __attribute__((address_space(1))) void*)g,
                                   (__attribute__((address_space(3))) void*)l, 16, 0, 0);
}

// ---------------- K0: [B][D][L] f32 -> [B][L][D] f16 (query & context) ------
__global__ __launch_bounds__(256) void transpose_cast(
    const float* __restrict__ q_in, const float* __restrict__ c_in,
    _Float16* __restrict__ q_out, _Float16* __restrict__ c_out)
{
  __shared__ float tile[64][68];
  const int which = blockIdx.z >> 2;
  const int b     = blockIdx.z & 3;
  const float* __restrict__ src = which ? c_in : q_in;
  _Float16* __restrict__ dst    = which ? c_out : q_out;
  const int l0 = blockIdx.x * 64, d0 = blockIdx.y * 64;
  const int tid = threadIdx.x;
  const int tr = tid >> 4, tc = (tid & 15) << 2;
#pragma unroll
  for (int i = 0; i < 4; ++i) {
    int d = tr + i * 16;
    f32x4 v = *(const f32x4*)(src + ((size_t)b * DDIM + d0 + d) * LSEQ + l0 + tc);
    *(f32x4*)&tile[d][tc] = v;
  }
  __syncthreads();
#pragma unroll
  for (int i = 0; i < 4; ++i) {
    int l = tr + i * 16;
    f16x4 h;
    h[0] = (_Float16)tile[tc + 0][l];
    h[1] = (_Float16)tile[tc + 1][l];
    h[2] = (_Float16)tile[tc + 2][l];
    h[3] = (_Float16)tile[tc + 3][l];
    *(f16x4*)(dst + ((size_t)b * LSEQ + l0 + l) * DDIM + d0 + tc) = h;
  }
}

// ---------------- K0b: W f32 -> f16 -----------------------------------------
__global__ __launch_bounds__(256) void wconv(const float* __restrict__ w,
                                             _Float16* __restrict__ w16) {
  int i = (blockIdx.x * 256 + threadIdx.x) * 4;
  f32x4 v = *(const f32x4*)(w + i);
  f16x4 h;
  h[0] = (_Float16)v[0]; h[1] = (_Float16)v[1];
  h[2] = (_Float16)v[2]; h[3] = (_Float16)v[3];
  *(f16x4*)(w16 + i) = h;
}

// ---------------- K0c: context [B][D][L] f32 -> f16 (same layout, pure cast)-
__global__ __launch_bounds__(256) void castD(const float* __restrict__ c_in,
                                             _Float16* __restrict__ cD16) {
  size_t i = ((size_t)blockIdx.x * 256 + threadIdx.x) * 8;
  f32x4 a = *(const f32x4*)(c_in + i);
  f32x4 b = *(const f32x4*)(c_in + i + 4);
  f16x8 h;
  h[0] = (_Float16)a[0]; h[1] = (_Float16)a[1];
  h[2] = (_Float16)a[2]; h[3] = (_Float16)a[3];
  h[4] = (_Float16)b[0]; h[5] = (_Float16)b[1];
  h[6] = (_Float16)b[2]; h[7] = (_Float16)b[3];
  *(f16x8*)(cD16 + i) = h;
}

// ---------------- K1: qw16 = qT16 @ W^T + bias ------------------------------
__global__ __launch_bounds__(256) void linear_q(
    const _Float16* __restrict__ qT16, const _Float16* __restrict__ W16,
    const float* __restrict__ bias, _Float16* __restrict__ qw16)
{
  const int tid = threadIdx.x;
  const int wv = tid >> 6, ln = tid & 63, g = ln >> 4, c16 = ln & 15;
  const size_t r0 = (size_t)blockIdx.x * 64 + wv * 16;

  f16x8 qa[8];
  const _Float16* qrow = qT16 + (r0 + c16) * DDIM + g * 8;
#pragma unroll
  for (int kk = 0; kk < 8; ++kk) qa[kk] = *(const f16x8*)(qrow + kk * 32);

  f32x4 acc[16];
#pragma unroll
  for (int n = 0; n < 16; ++n) acc[n] = f32x4{0.f, 0.f, 0.f, 0.f};

#pragma unroll 2
  for (int kk = 0; kk < 8; ++kk) {
#pragma unroll
    for (int n = 0; n < 16; ++n) {
      f16x8 bf = *(const f16x8*)(W16 + (n * 16 + c16) * DDIM + kk * 32 + g * 8);
      acc[n] = __builtin_amdgcn_mfma_f32_16x16x32_f16(qa[kk], bf, acc[n], 0, 0, 0);
    }
  }
#pragma unroll
  for (int n = 0; n < 16; ++n) {
    float bb = bias[n * 16 + c16];
#pragma unroll
    for (int r = 0; r < 4; ++r)
      qw16[(r0 + 4 * g + r) * DDIM + n * 16 + c16] = (_Float16)(acc[n][r] + bb);
  }
}

// ---------------- K2: fused attention ---------------------------------------
// c_lds  (q-major): byte = q*512 + d*2            ^ ((q&7)<<4)   [scores B]
// c_lds2 (d-major): byte = d*128 + (q-q0)*2       ^ ((d&7)<<4)   [PV B]
// w_lds  (shared) : byte = row*128 + q*2          ^ ((row&7)<<4) [PV A]
// All reads 2-lanes-per-bank-group per 16-lane phase (conflict floor).
// DMA staging: linear LDS dest + inverse-swizzled global source (rule #21).
__global__ __launch_bounds__(256) void attn_main(
    const _Float16* __restrict__ qw16,
    const _Float16* __restrict__ cT16,
    const _Float16* __restrict__ cD16,
    float* __restrict__ outp,
    float* __restrict__ wgt)
{
  __shared__ __align__(16) char smem[2][65536];  // [p][ c_lds 32K | c_lds2 32K ]
  __shared__ __align__(16) char wbuf[8192];      // 64 rows x 64 q f16, swizzled

  const int tid = threadIdx.x;
  const int wv  = tid >> 6;
  const int ln  = tid & 63;
  const int g   = ln >> 4;
  const int c16 = ln & 15;

  // batch -> XCD-pair remap (context tiles stay L2-resident)
  const int lin   = blockIdx.y * 64 + blockIdx.x;
  const int b     = (lin & 7) >> 1;
  const int otile = ((lin >> 3) << 1) | (lin & 1);
  const int o0    = otile * 64;
  const int bo    = b * LSEQ + o0;

  const _Float16* __restrict__ cbase = cT16 + (size_t)b * LSEQ * DDIM;
  const _Float16* __restrict__ cDb   = cD16 + (size_t)b * DDIM * LSEQ;

  // qw A-frags: wave's 16 rows, K=256
  f16x8 qa[8];
  {
    const _Float16* qrow = qw16 + ((size_t)bo + wv * 16 + c16) * DDIM + g * 8;
#pragma unroll
    for (int kk = 0; kk < 8; ++kk) qa[kk] = *(const f16x8*)(qrow + kk * 32);
  }

  auto issueA = [&](int q0s, int p) {  // stage c_lds (scores operand)
#pragma unroll
    for (int i = 0; i < 8; ++i) {
      unsigned x  = (unsigned)(wv * 8192 + i * 1024 + ln * 16);
      unsigned q  = x >> 9;
      unsigned db = (x & 511u) ^ ((q & 7u) << 4);
      gld16(cbase + (size_t)(q0s + q) * DDIM + (db >> 1),
            &smem[p][wv * 8192 + i * 1024]);
    }
  };
  auto issueC2 = [&](int q0s, int p) {  // stage c_lds2 (PV operand)
#pragma unroll
    for (int i = 0; i < 8; ++i) {
      unsigned x  = (unsigned)(wv * 8192 + i * 1024 + ln * 16);
      unsigned d  = x >> 7;
      unsigned qb = (x & 127u) ^ ((d & 7u) << 4);
      gld16(cDb + (size_t)d * LSEQ + q0s + (qb >> 1),
            &smem[p][32768 + wv * 8192 + i * 1024]);
    }
  };

  auto scores = [&](int p, f32x4 sa[4]) {
    const char* cl = smem[p];
#pragma unroll
    for (int qf = 0; qf < 4; ++qf) sa[qf] = f32x4{0.f, 0.f, 0.f, 0.f};
#pragma unroll
    for (int kk = 0; kk < 8; ++kk) {
#pragma unroll
      for (int qf = 0; qf < 4; ++qf) {
        unsigned off = (unsigned)(((qf * 16 + c16) * 512 + kk * 64 + g * 16)) ^
                       ((unsigned)(c16 & 7) << 4);
        f16x8 bf = *(const f16x8*)(cl + off);
        sa[qf] = __builtin_amdgcn_mfma_f32_16x16x32_f16(qa[kk], bf, sa[qf], 0, 0, 0);
      }
    }
  };

  // ---- phase A: per-row sum of exp(s)
  float lsum[4] = {0.f, 0.f, 0.f, 0.f};
  int p = 0;
  issueA(0, 0);
  for (int t = 0; t < LSEQ / TQ; ++t) {
    asm volatile("s_waitcnt vmcnt(0)" ::: "memory");
    __builtin_amdgcn_s_barrier();
    if (t < LSEQ / TQ - 1) {
      issueA((t + 1) * TQ, p ^ 1);
    } else {
      issueA(0, p ^ 1);
      issueC2(0, p ^ 1);
    }
    __builtin_amdgcn_sched_barrier(0);
    f32x4 sa[4];
    scores(p, sa);
#pragma unroll
    for (int qf = 0; qf < 4; ++qf)
#pragma unroll
      for (int r = 0; r < 4; ++r) lsum[r] += __expf(sa[qf][r]);
    p ^= 1;
  }

  float invl[4];
#pragma unroll
  for (int r = 0; r < 4; ++r) {
    float v = lsum[r];
    v += __shfl_xor(v, 1);
    v += __shfl_xor(v, 2);
    v += __shfl_xor(v, 4);
    v += __shfl_xor(v, 8);
    invl[r] = 1.0f / v;
  }

  // ---- phase B: recompute, write weights, PV (n-slice decomposition)
  f32x4 oacc[4][4];
#pragma unroll
  for (int m = 0; m < 4; ++m)
#pragma unroll
    for (int nf = 0; nf < 4; ++nf) oacc[m][nf] = f32x4{0.f, 0.f, 0.f, 0.f};

  for (int t = 0; t < LSEQ / TQ; ++t) {
    // wait the 16 oldest vmem ops (this tile's DMA); wgt stores may still fly
    if (t == 0) asm volatile("s_waitcnt vmcnt(0)" ::: "memory");
    else        asm volatile("s_waitcnt vmcnt(16)" ::: "memory");
    __builtin_amdgcn_s_barrier();
    if (t < LSEQ / TQ - 1) {
      issueA((t + 1) * TQ, p ^ 1);
      issueC2((t + 1) * TQ, p ^ 1);
    }
    __builtin_amdgcn_sched_barrier(0);

    const int q0 = t * TQ;
    f32x4 sa[4];
    scores(p, sa);

#pragma unroll
    for (int qf = 0; qf < 4; ++qf) {
#pragma unroll
      for (int r = 0; r < 4; ++r) {
        float w = __expf(sa[qf][r]) * invl[r];
        wgt[(size_t)(bo + wv * 16 + 4 * g + r) * LSEQ + (q0 + qf * 16 + c16)] = w;
        unsigned wb = (unsigned)((wv * 16 + 4 * g + r) * 128 + (qf * 16 + c16) * 2) ^
                      ((unsigned)((4 * g + r) & 7) << 4);
        *(_Float16*)(wbuf + wb) = (_Float16)w;
      }
    }
    // all waves' w_lds writes visible before PV A-frag reads
    asm volatile("s_waitcnt lgkmcnt(0)" ::: "memory");
    __builtin_amdgcn_s_barrier();
    __builtin_amdgcn_sched_barrier(0);

    const char* cl2 = smem[p] + 32768;
#pragma unroll
    for (int kq = 0; kq < 2; ++kq) {
      f16x8 wa[4], bv[4];
#pragma unroll
      for (int m = 0; m < 4; ++m) {
        unsigned off = (unsigned)((m * 16 + c16) * 128 + kq * 64 + g * 16) ^
                       ((unsigned)(c16 & 7) << 4);
        wa[m] = *(const f16x8*)(wbuf + off);
      }
#pragma unroll
      for (int nf = 0; nf < 4; ++nf) {
        unsigned off = (unsigned)((wv * 64 + nf * 16 + c16) * 128 + kq * 64 + g * 16) ^
                       ((unsigned)(c16 & 7) << 4);
        bv[nf] = *(const f16x8*)(cl2 + off);
      }
#pragma unroll
      for (int m = 0; m < 4; ++m)
#pragma unroll
        for (int nf = 0; nf < 4; ++nf)
          oacc[m][nf] =
              __builtin_amdgcn_mfma_f32_16x16x32_f16(wa[m], bv[nf], oacc[m][nf], 0, 0, 0);
    }
    p ^= 1;
  }

  // ---- epilogue: wave wv owns all 64 rows x d-cols [wv*64, wv*64+64)
#pragma unroll
  for (int m = 0; m < 4; ++m)
#pragma unroll
    for (int nf = 0; nf < 4; ++nf)
#pragma unroll
      for (int r = 0; r < 4; ++r)
        outp[(size_t)(bo + m * 16 + 4 * g + r) * DDIM + wv * 64 + nf * 16 + c16] =
            oacc[m][nf][r];
}

extern "C" void kernel_launch(void* const* d_in, const int* in_sizes, int n_in,
                              void* d_out, int out_size, void* d_ws, size_t ws_size,
                              hipStream_t stream) {
  const float* query   = (const float*)d_in[0];
  const float* context = (const float*)d_in[1];
  const float* W_in    = (const float*)d_in[2];
  const float* b_in    = (const float*)d_in[3];

  float* outp = (float*)d_out;
  float* wgt  = outp + (size_t)BATCH * LSEQ * DDIM;  // outputs concat: out, weights

  const size_t NELEM = (size_t)BATCH * LSEQ * DDIM;  // 4,194,304
  _Float16* qT16 = (_Float16*)d_ws;
  _Float16* cT16 = qT16 + NELEM;
  _Float16* qw16 = cT16 + NELEM;
  _Float16* W16  = qw16 + NELEM;   // +65536 halfs; total ws use = 25.3 MB
  _Float16* cD16 = qT16;           // aliases qT16 (dead after linear_q)

  transpose_cast<<<dim3(LSEQ / 64, DDIM / 64, 2 * BATCH), 256, 0, stream>>>(
      query, context, qT16, cT16);
  wconv<<<(DDIM * DDIM) / 1024, 256, 0, stream>>>(W_in, W16);
  linear_q<<<(BATCH * LSEQ) / 64, 256, 0, stream>>>(qT16, W16, b_in, qw16);
  castD<<<(int)(NELEM / 2048), 256, 0, stream>>>(context, cD16);
  attn_main<<<dim3(64, BATCH), 256, 0, stream>>>(qw16, cT16, cD16, outp, wgt);
}

// Round 6
// 276.787 us; speedup vs baseline: 1.9463x; 1.1433x over previous
//
#include <hip/hip_runtime.h>

// Luong 'general' attention, B=4 D=256 L=4096.
// K0 transpose/cast q,c -> [B][L][D] f16 ; K0b W f32->f16 ; K1 MFMA linear qw=q@W^T+b ;
// K0c context cast [B][D][L] f32->f16 (aliases qT16, dead after K1) ;
// K2 fused attn, 512 thr / 8 waves (2 per SIMD), q-split halves:
//   wave (rw,h): rows rw*16..+16, q-half h*32..+32 of each 64-q tile.
//   phase A: l=sum(exp(s)) per row (no max-sub: |s|<~35, f32 exp safe)
//   phase B: recompute s (bit-identical), w=exp(s)/l -> global + w_lds(f16),
//            PV from c_lds2 (d-major LDS); per-half oacc summed via LDS at end.
// LDS: 2 x (32KB c_lds q-major + 32KB c_lds2 d-major) + 8KB w_lds + 0.5KB red = 140 KB.
// ws usage: 25.3 MB.

#define BATCH 4
#define DDIM  256
#define LSEQ  4096
#define TQ    64

typedef float    f32x4 __attribute__((ext_vector_type(4)));
typedef _Float16 f16x8 __attribute__((ext_vector_type(8)));
typedef _Float16 f16x4 __attribute__((ext_vector_type(4)));

__device__ __forceinline__ void gld16(const void* g, void* l) {
  __builtin_amdgcn_global_load_lds((const __attribute__((address_space(1))) void*)g,
                                   (__attribute__((address_space(3))) void*)l, 16, 0, 0);
}

// ---------------- K0: [B][D][L] f32 -> [B][L][D] f16 (query & context) ------
__global__ __launch_bounds__(256) void transpose_cast(
    const float* __restrict__ q_in, const float* __restrict__ c_in,
    _Float16* __restrict__ q_out, _Float16* __restrict__ c_out)
{
  __shared__ float tile[64][68];
  const int which = blockIdx.z >> 2;
  const int b     = blockIdx.z & 3;
  const float* __restrict__ src = which ? c_in : q_in;
  _Float16* __restrict__ dst    = which ? c_out : q_out;
  const int l0 = blockIdx.x * 64, d0 = blockIdx.y * 64;
  const int tid = threadIdx.x;
  const int tr = tid >> 4, tc = (tid & 15) << 2;
#pragma unroll
  for (int i = 0; i < 4; ++i) {
    int d = tr + i * 16;
    f32x4 v = *(const f32x4*)(src + ((size_t)b * DDIM + d0 + d) * LSEQ + l0 + tc);
    *(f32x4*)&tile[d][tc] = v;
  }
  __syncthreads();
#pragma unroll
  for (int i = 0; i < 4; ++i) {
    int l = tr + i * 16;
    f16x4 h;
    h[0] = (_Float16)tile[tc + 0][l];
    h[1] = (_Float16)tile[tc + 1][l];
    h[2] = (_Float16)tile[tc + 2][l];
    h[3] = (_Float16)tile[tc + 3][l];
    *(f16x4*)(dst + ((size_t)b * LSEQ + l0 + l) * DDIM + d0 + tc) = h;
  }
}

// ---------------- K0b: W f32 -> f16 -----------------------------------------
__global__ __launch_bounds__(256) void wconv(const float* __restrict__ w,
                                             _Float16* __restrict__ w16) {
  int i = (blockIdx.x * 256 + threadIdx.x) * 4;
  f32x4 v = *(const f32x4*)(w + i);
  f16x4 h;
  h[0] = (_Float16)v[0]; h[1] = (_Float16)v[1];
  h[2] = (_Float16)v[2]; h[3] = (_Float16)v[3];
  *(f16x4*)(w16 + i) = h;
}

// ---------------- K0c: context [B][D][L] f32 -> f16 (same layout, pure cast)-
__global__ __launch_bounds__(256) void castD(const float* __restrict__ c_in,
                                             _Float16* __restrict__ cD16) {
  size_t i = ((size_t)blockIdx.x * 256 + threadIdx.x) * 8;
  f32x4 a = *(const f32x4*)(c_in + i);
  f32x4 b = *(const f32x4*)(c_in + i + 4);
  f16x8 h;
  h[0] = (_Float16)a[0]; h[1] = (_Float16)a[1];
  h[2] = (_Float16)a[2]; h[3] = (_Float16)a[3];
  h[4] = (_Float16)b[0]; h[5] = (_Float16)b[1];
  h[6] = (_Float16)b[2]; h[7] = (_Float16)b[3];
  *(f16x8*)(cD16 + i) = h;
}

// ---------------- K1: qw16 = qT16 @ W^T + bias ------------------------------
__global__ __launch_bounds__(256) void linear_q(
    const _Float16* __restrict__ qT16, const _Float16* __restrict__ W16,
    const float* __restrict__ bias, _Float16* __restrict__ qw16)
{
  const int tid = threadIdx.x;
  const int wv = tid >> 6, ln = tid & 63, g = ln >> 4, c16 = ln & 15;
  const size_t r0 = (size_t)blockIdx.x * 64 + wv * 16;

  f16x8 qa[8];
  const _Float16* qrow = qT16 + (r0 + c16) * DDIM + g * 8;
#pragma unroll
  for (int kk = 0; kk < 8; ++kk) qa[kk] = *(const f16x8*)(qrow + kk * 32);

  f32x4 acc[16];
#pragma unroll
  for (int n = 0; n < 16; ++n) acc[n] = f32x4{0.f, 0.f, 0.f, 0.f};

#pragma unroll 2
  for (int kk = 0; kk < 8; ++kk) {
#pragma unroll
    for (int n = 0; n < 16; ++n) {
      f16x8 bf = *(const f16x8*)(W16 + (n * 16 + c16) * DDIM + kk * 32 + g * 8);
      acc[n] = __builtin_amdgcn_mfma_f32_16x16x32_f16(qa[kk], bf, acc[n], 0, 0, 0);
    }
  }
#pragma unroll
  for (int n = 0; n < 16; ++n) {
    float bb = bias[n * 16 + c16];
#pragma unroll
    for (int r = 0; r < 4; ++r)
      qw16[(r0 + 4 * g + r) * DDIM + n * 16 + c16] = (_Float16)(acc[n][r] + bb);
  }
}

// ---------------- K2: fused attention (8 waves, q-split) --------------------
// c_lds  (q-major): byte = q*512 + d*2        ^ ((q&7)<<4)   [scores B]
// c_lds2 (d-major): byte = d*128 + (q-q0)*2   ^ ((d&7)<<4)   [PV B]
// w_lds  (shared) : byte = row*128 + q*2      ^ ((row&7)<<4) [PV A]
// DMA staging: linear LDS dest + inverse-swizzled global source (rule #21).
__global__ __launch_bounds__(512) void attn_main(
    const _Float16* __restrict__ qw16,
    const _Float16* __restrict__ cT16,
    const _Float16* __restrict__ cD16,
    float* __restrict__ outp,
    float* __restrict__ wgt)
{
  __shared__ __align__(16) char smem[2][65536];  // [p][ c_lds 32K | c_lds2 32K ]
  __shared__ __align__(16) char wbuf[8192];      // 64 rows x 64 q f16, swizzled
  __shared__ float redbuf[2][64];                // per-half row sums

  const int tid = threadIdx.x;
  const int wv  = tid >> 6;       // 0..7
  const int rw  = wv >> 1;        // row-wave 0..3
  const int h   = wv & 1;         // q-half 0..1
  const int ln  = tid & 63;
  const int g   = ln >> 4;
  const int c16 = ln & 15;

  // batch -> XCD-pair remap (context tiles stay L2-resident)
  const int lin   = blockIdx.y * 64 + blockIdx.x;
  const int b     = (lin & 7) >> 1;
  const int otile = ((lin >> 3) << 1) | (lin & 1);
  const int o0    = otile * 64;
  const int bo    = b * LSEQ + o0;

  const _Float16* __restrict__ cbase = cT16 + (size_t)b * LSEQ * DDIM;
  const _Float16* __restrict__ cDb   = cD16 + (size_t)b * DDIM * LSEQ;

  // qw A-frags: wave's 16 rows (rw*16..), K=256
  f16x8 qa[8];
  {
    const _Float16* qrow = qw16 + ((size_t)bo + rw * 16 + c16) * DDIM + g * 8;
#pragma unroll
    for (int kk = 0; kk < 8; ++kk) qa[kk] = *(const f16x8*)(qrow + kk * 32);
  }

  auto issueA = [&](int q0s, int p) {  // stage c_lds (scores operand): 4 KB/wave
#pragma unroll
    for (int i = 0; i < 4; ++i) {
      unsigned x  = (unsigned)(wv * 4096 + i * 1024 + ln * 16);
      unsigned q  = x >> 9;
      unsigned db = (x & 511u) ^ ((q & 7u) << 4);
      gld16(cbase + (size_t)(q0s + q) * DDIM + (db >> 1),
            &smem[p][wv * 4096 + i * 1024]);
    }
  };
  auto issueC2 = [&](int q0s, int p) {  // stage c_lds2 (PV operand): 4 KB/wave
#pragma unroll
    for (int i = 0; i < 4; ++i) {
      unsigned x  = (unsigned)(wv * 4096 + i * 1024 + ln * 16);
      unsigned d  = x >> 7;
      unsigned qb = (x & 127u) ^ ((d & 7u) << 4);
      gld16(cDb + (size_t)d * LSEQ + q0s + (qb >> 1),
            &smem[p][32768 + wv * 4096 + i * 1024]);
    }
  };

  // wave (rw,h): q-cols h*32 + qf*16 + c16, qf in {0,1}
  auto scores = [&](int p, f32x4 sa[2]) {
    const char* cl = smem[p];
#pragma unroll
    for (int qf = 0; qf < 2; ++qf) sa[qf] = f32x4{0.f, 0.f, 0.f, 0.f};
#pragma unroll
    for (int kk = 0; kk < 8; ++kk) {
#pragma unroll
      for (int qf = 0; qf < 2; ++qf) {
        unsigned off = (unsigned)(((h * 32 + qf * 16 + c16) * 512 + kk * 64 + g * 16)) ^
                       ((unsigned)(c16 & 7) << 4);
        f16x8 bf = *(const f16x8*)(cl + off);
        sa[qf] = __builtin_amdgcn_mfma_f32_16x16x32_f16(qa[kk], bf, sa[qf], 0, 0, 0);
      }
    }
  };

  // ---- phase A: per-row sum of exp(s) over this wave's q-half
  float lsum[4] = {0.f, 0.f, 0.f, 0.f};
  int p = 0;
  issueA(0, 0);
  for (int t = 0; t < LSEQ / TQ; ++t) {
    asm volatile("s_waitcnt vmcnt(0)" ::: "memory");
    __builtin_amdgcn_s_barrier();
    if (t < LSEQ / TQ - 1) {
      issueA((t + 1) * TQ, p ^ 1);
    } else {
      issueA(0, p ^ 1);
      issueC2(0, p ^ 1);
    }
    __builtin_amdgcn_sched_barrier(0);
    f32x4 sa[2];
    scores(p, sa);
#pragma unroll
    for (int r = 0; r < 4; ++r) lsum[r] += __expf(sa[0][r]) + __expf(sa[1][r]);
    p ^= 1;
  }

  // intra-wave reduce over the 16 q-cols, then cross-half via redbuf
#pragma unroll
  for (int r = 0; r < 4; ++r) {
    float v = lsum[r];
    v += __shfl_xor(v, 1);
    v += __shfl_xor(v, 2);
    v += __shfl_xor(v, 4);
    v += __shfl_xor(v, 8);
    lsum[r] = v;
  }
  if (c16 == 0) {
#pragma unroll
    for (int r = 0; r < 4; ++r) redbuf[h][rw * 16 + 4 * g + r] = lsum[r];
  }
  __syncthreads();
  float invl[4];
#pragma unroll
  for (int r = 0; r < 4; ++r)
    invl[r] = 1.0f / (redbuf[0][rw * 16 + 4 * g + r] + redbuf[1][rw * 16 + 4 * g + r]);

  // ---- phase B: recompute, write weights, PV (d-slice by rw, k-half by h)
  f32x4 oacc[4][4];
#pragma unroll
  for (int m = 0; m < 4; ++m)
#pragma unroll
    for (int nf = 0; nf < 4; ++nf) oacc[m][nf] = f32x4{0.f, 0.f, 0.f, 0.f};

  for (int t = 0; t < LSEQ / TQ; ++t) {
    // 8 oldest outstanding = this tile's DMA; wgt stores (newest 8) may still fly
    if (t == 0) asm volatile("s_waitcnt vmcnt(0)" ::: "memory");
    else        asm volatile("s_waitcnt vmcnt(8)" ::: "memory");
    __builtin_amdgcn_s_barrier();
    if (t < LSEQ / TQ - 1) {
      issueA((t + 1) * TQ, p ^ 1);
      issueC2((t + 1) * TQ, p ^ 1);
    }
    __builtin_amdgcn_sched_barrier(0);

    const int q0 = t * TQ;
    f32x4 sa[2];
    scores(p, sa);

#pragma unroll
    for (int qf = 0; qf < 2; ++qf) {
#pragma unroll
      for (int r = 0; r < 4; ++r) {
        float w = __expf(sa[qf][r]) * invl[r];
        int row = rw * 16 + 4 * g + r;
        int col = h * 32 + qf * 16 + c16;
        wgt[(size_t)(bo + row) * LSEQ + (q0 + col)] = w;
        unsigned wb = (unsigned)(row * 128 + col * 2) ^
                      ((unsigned)((4 * g + r) & 7) << 4);
        *(_Float16*)(wbuf + wb) = (_Float16)w;
      }
    }
    // all waves' w_lds writes visible before PV A-frag reads
    asm volatile("s_waitcnt lgkmcnt(0)" ::: "memory");
    __builtin_amdgcn_s_barrier();
    __builtin_amdgcn_sched_barrier(0);

    const char* cl2 = smem[p] + 32768;
    {
      f16x8 wa[4], bv[4];
#pragma unroll
      for (int m = 0; m < 4; ++m) {
        unsigned off = (unsigned)((m * 16 + c16) * 128 + h * 64 + g * 16) ^
                       ((unsigned)(c16 & 7) << 4);
        wa[m] = *(const f16x8*)(wbuf + off);
      }
#pragma unroll
      for (int nf = 0; nf < 4; ++nf) {
        unsigned off = (unsigned)((rw * 64 + nf * 16 + c16) * 128 + h * 64 + g * 16) ^
                       ((unsigned)(c16 & 7) << 4);
        bv[nf] = *(const f16x8*)(cl2 + off);
      }
#pragma unroll
      for (int m = 0; m < 4; ++m)
#pragma unroll
        for (int nf = 0; nf < 4; ++nf)
          oacc[m][nf] =
              __builtin_amdgcn_mfma_f32_16x16x32_f16(wa[m], bv[nf], oacc[m][nf], 0, 0, 0);
    }
    p ^= 1;
  }

  // ---- cross-half PV sum via LDS (smem[0] is dead), then store out
  if (h == 1) {
#pragma unroll
    for (int m = 0; m < 4; ++m)
#pragma unroll
      for (int nf = 0; nf < 4; ++nf)
        *(f32x4*)(smem[0] + rw * 16384 + (m * 4 + nf) * 1024 + ln * 16) = oacc[m][nf];
  }
  __syncthreads();
  if (h == 0) {
#pragma unroll
    for (int m = 0; m < 4; ++m)
#pragma unroll
      for (int nf = 0; nf < 4; ++nf) {
        f32x4 o2 = *(const f32x4*)(smem[0] + rw * 16384 + (m * 4 + nf) * 1024 + ln * 16);
        f32x4 o  = oacc[m][nf] + o2;
#pragma unroll
        for (int r = 0; r < 4; ++r)
          outp[(size_t)(bo + m * 16 + 4 * g + r) * DDIM + rw * 64 + nf * 16 + c16] = o[r];
      }
  }
}

extern "C" void kernel_launch(void* const* d_in, const int* in_sizes, int n_in,
                              void* d_out, int out_size, void* d_ws, size_t ws_size,
                              hipStream_t stream) {
  const float* query   = (const float*)d_in[0];
  const float* context = (const float*)d_in[1];
  const float* W_in    = (const float*)d_in[2];
  const float* b_in    = (const float*)d_in[3];

  float* outp = (float*)d_out;
  float* wgt  = outp + (size_t)BATCH * LSEQ * DDIM;  // outputs concat: out, weights

  const size_t NELEM = (size_t)BATCH * LSEQ * DDIM;  // 4,194,304
  _Float16* qT16 = (_Float16*)d_ws;
  _Float16* cT16 = qT16 + NELEM;
  _Float16* qw16 = cT16 + NELEM;
  _Float16* W16  = qw16 + NELEM;   // +65536 halfs; total ws use = 25.3 MB
  _Float16* cD16 = qT16;           // aliases qT16 (dead after linear_q)

  transpose_cast<<<dim3(LSEQ / 64, DDIM / 64, 2 * BATCH), 256, 0, stream>>>(
      query, context, qT16, cT16);
  wconv<<<(DDIM * DDIM) / 1024, 256, 0, stream>>>(W_in, W16);
  linear_q<<<(BATCH * LSEQ) / 64, 256, 0, stream>>>(qT16, W16, b_in, qw16);
  castD<<<(int)(NELEM / 2048), 256, 0, stream>>>(context, cD16);
  attn_main<<<dim3(64, BATCH), 512, 0, stream>>>(qw16, cT16, cD16, outp, wgt);
}